// Round 1
// baseline (169.291 us; speedup 1.0000x reference)
//
#include <hip/hip_runtime.h>
#include <hip/hip_bf16.h>
#include <stdint.h>

typedef float  f32x4  __attribute__((ext_vector_type(4)));
typedef __bf16 bf16x8 __attribute__((ext_vector_type(8)));

// ---------------- projection GEMM ----------------
// D[o][n] = sum_c W[o][c] * X[b][c][hw(n)],  n = token-major pixel index.
// Tile: BM=128 (out-ch) x BN=128 (pixels = 8 tokens) x BK=32, 4 waves (2x2).
// Output written as bf16 token layout: [b][tok][c][16] for the attention kernel.

#define BM 128
#define BN 128
#define BK 32
#define LROW 40   // bf16 elems per LDS row (32 data + 8 pad) => 80B stride, breaks bank conflicts

__global__ __launch_bounds__(256) void proj_gemm_kernel(
    const float* __restrict__ blue, const float* __restrict__ white,
    const float* __restrict__ Wq, const float* __restrict__ bq,
    const float* __restrict__ Wk, const float* __restrict__ bk,
    const float* __restrict__ Wv, const float* __restrict__ bv,
    __bf16* __restrict__ Qt, __bf16* __restrict__ Kt, __bf16* __restrict__ Vt)
{
  __shared__ __bf16 As[BM * LROW];
  __shared__ __bf16 Bs[BN * LROW];

  const int bid    = blockIdx.x;
  const int tensor = bid / 512;           // 0:Q 1:K 2:V
  const int rest   = bid - tensor * 512;
  const int ob     = rest >> 8;           // 0..1  (o-block of 128)
  const int nb     = rest & 255;          // 0..255 (n-block of 128)

  const float* X    = (tensor == 0) ? blue : white;
  const float* W    = (tensor == 0) ? Wq : (tensor == 1) ? Wk : Wv;
  const float* bias = (tensor == 0) ? bq : (tensor == 1) ? bk : bv;
  __bf16*      Out  = (tensor == 0) ? Qt : (tensor == 1) ? Kt : Vt;

  const int tid  = threadIdx.x;
  const int lane = tid & 63;
  const int wave = tid >> 6;
  const int wo   = wave >> 1;   // o half (64)
  const int wn   = wave & 1;    // n half (64)

  const int o0 = ob * BM;
  const int n0 = nb * BN;
  const int batch = n0 >> 12;         // 4096 pixels per image
  const int p0    = n0 & 4095;
  const int ti    = (p0 >> 4) >> 4;   // token row (tokens are 16-aligned in n)
  const int tj0   = (p0 >> 4) & 15;   // first token col in this tile (0 or 8)

  const float* Xb = X + (size_t)batch * (256 * 4096);

  f32x4 acc[4][4];
#pragma unroll
  for (int i = 0; i < 4; ++i)
#pragma unroll
    for (int j = 0; j < 4; ++j) acc[i][j] = (f32x4)0.0f;

  // staging roles
  const int arow  = tid >> 1;   // 0..127 weight row
  const int ahalf = tid & 1;    // 16 k's each
  const int bq5   = tid & 31;   // B: (token-local, row-in-token)
  const int btl   = bq5 >> 2;   // 0..7 token within tile
  const int brw   = bq5 & 3;    // 0..3 row within token
  const int bc8   = tid >> 5;   // 0..7 channel sub-index

  const int lrow = lane & 15;
  const int lk   = (lane >> 4) * 8;

  for (int kk = 0; kk < 8; ++kk) {
    const int k0 = kk * BK;
    // ---- stage A: W[o0..o0+127][k0..k0+31], f32 -> bf16, row-major
    {
      const float* src = W + (size_t)(o0 + arow) * 256 + k0 + ahalf * 16;
      float tmp[16] __attribute__((aligned(16)));
      *(f32x4*)(tmp + 0)  = *(const f32x4*)(src + 0);
      *(f32x4*)(tmp + 4)  = *(const f32x4*)(src + 4);
      *(f32x4*)(tmp + 8)  = *(const f32x4*)(src + 8);
      *(f32x4*)(tmp + 12) = *(const f32x4*)(src + 12);
      __bf16 cv[16] __attribute__((aligned(16)));
#pragma unroll
      for (int t = 0; t < 16; ++t) cv[t] = (__bf16)tmp[t];
      __bf16* dst = As + arow * LROW + ahalf * 16;
      *(bf16x8*)(dst + 0) = *(bf16x8*)(cv + 0);
      *(bf16x8*)(dst + 8) = *(bf16x8*)(cv + 8);
    }
    // ---- stage B: X[c][hw] -> Bs[n][c] (transpose during staging)
#pragma unroll
    for (int it = 0; it < 4; ++it) {
      const int c  = bc8 + it * 8;                       // 0..31
      const int hw = (ti * 4 + brw) * 64 + (tj0 + btl) * 4;
      const float* src = Xb + (size_t)(k0 + c) * 4096 + hw;
      f32x4 v = *(const f32x4*)src;                      // 4 pixels (d minor)
      const int nloc = btl * 16 + brw * 4;
      Bs[(nloc + 0) * LROW + c] = (__bf16)v[0];
      Bs[(nloc + 1) * LROW + c] = (__bf16)v[1];
      Bs[(nloc + 2) * LROW + c] = (__bf16)v[2];
      Bs[(nloc + 3) * LROW + c] = (__bf16)v[3];
    }
    __syncthreads();

    bf16x8 a[4], b[4];
#pragma unroll
    for (int i = 0; i < 4; ++i)
      a[i] = *(const bf16x8*)(As + (wo * 64 + i * 16 + lrow) * LROW + lk);
#pragma unroll
    for (int j = 0; j < 4; ++j)
      b[j] = *(const bf16x8*)(Bs + (wn * 64 + j * 16 + lrow) * LROW + lk);
#pragma unroll
    for (int i = 0; i < 4; ++i)
#pragma unroll
      for (int j = 0; j < 4; ++j)
        acc[i][j] = __builtin_amdgcn_mfma_f32_16x16x32_bf16(a[i], b[j], acc[i][j], 0, 0, 0);
    __syncthreads();
  }

  // ---- epilogue: bias add, write token-major bf16: [(b*256+t)*256 + o]*16 + d
#pragma unroll
  for (int i = 0; i < 4; ++i) {
    const int obase = o0 + wo * 64 + i * 16 + (lane >> 4) * 4;
#pragma unroll
    for (int j = 0; j < 4; ++j) {
      const int n  = n0 + wn * 64 + j * 16 + (lane & 15);
      const int bb = n >> 12;
      const int p  = n & 4095;
      const int t  = p >> 4;
      const int d  = p & 15;
      const size_t base = (((size_t)bb * 256 + t) * 256) * 16 + d;
#pragma unroll
      for (int r = 0; r < 4; ++r) {
        const int o = obase + r;
        const float v = acc[i][j][r] + bias[o];
        Out[base + (size_t)o * 16] = (__bf16)v;
      }
    }
  }
}

// ---------------- fused neighborhood attention + residual ----------------
// block = one (b, token), thread = one channel. Zero-padded neighbors:
// OOB logit = 0 (included in softmax denom), OOB V contributes nothing.

__device__ __forceinline__ void unpack8(const uint4 v, float* f) {
  const uint32_t u0 = v.x, u1 = v.y, u2 = v.z, u3 = v.w;
  f[0] = __uint_as_float(u0 << 16); f[1] = __uint_as_float(u0 & 0xffff0000u);
  f[2] = __uint_as_float(u1 << 16); f[3] = __uint_as_float(u1 & 0xffff0000u);
  f[4] = __uint_as_float(u2 << 16); f[5] = __uint_as_float(u2 & 0xffff0000u);
  f[6] = __uint_as_float(u3 << 16); f[7] = __uint_as_float(u3 & 0xffff0000u);
}

__global__ __launch_bounds__(256) void attn_kernel(
    const __bf16* __restrict__ Qt, const __bf16* __restrict__ Kt,
    const __bf16* __restrict__ Vt, const float* __restrict__ blue,
    float* __restrict__ out)
{
  const int bid = blockIdx.x;     // 0..2047
  const int b  = bid >> 8;
  const int t  = bid & 255;
  const int ti = t >> 4;
  const int tj = t & 15;
  const int c  = threadIdx.x;     // channel

  const size_t qbase = (((size_t)b * 256 + t) * 256 + c) * 16;
  float q[16];
  unpack8(*(const uint4*)(Qt + qbase), q);
  unpack8(*(const uint4*)(Qt + qbase + 8), q + 8);

  float s[9];
#pragma unroll
  for (int n = 0; n < 9; ++n) {
    const int yi = ti + n / 3 - 1;
    const int yj = tj + n % 3 - 1;
    float dot = 0.0f;
    if (yi >= 0 && yi < 16 && yj >= 0 && yj < 16) {   // uniform per block
      const size_t kb = (((size_t)b * 256 + (yi * 16 + yj)) * 256 + c) * 16;
      float kf[16];
      unpack8(*(const uint4*)(Kt + kb), kf);
      unpack8(*(const uint4*)(Kt + kb + 8), kf + 8);
#pragma unroll
      for (int d = 0; d < 16; ++d) dot = fmaf(q[d], kf[d], dot);
    }
    s[n] = dot * 0.25f;     // scale = (ts*ts)^-0.5 ; OOB logit stays 0
  }

  float m = s[0];
#pragma unroll
  for (int n = 1; n < 9; ++n) m = fmaxf(m, s[n]);
  float w[9], denom = 0.0f;
#pragma unroll
  for (int n = 0; n < 9; ++n) { w[n] = __expf(s[n] - m); denom += w[n]; }
  const float inv = 1.0f / denom;

  float o16[16];
#pragma unroll
  for (int d = 0; d < 16; ++d) o16[d] = 0.0f;
#pragma unroll
  for (int n = 0; n < 9; ++n) {
    const int yi = ti + n / 3 - 1;
    const int yj = tj + n % 3 - 1;
    if (yi >= 0 && yi < 16 && yj >= 0 && yj < 16) {
      const size_t vb = (((size_t)b * 256 + (yi * 16 + yj)) * 256 + c) * 16;
      float vf[16];
      unpack8(*(const uint4*)(Vt + vb), vf);
      unpack8(*(const uint4*)(Vt + vb + 8), vf + 8);
#pragma unroll
      for (int d = 0; d < 16; ++d) o16[d] = fmaf(w[n], vf[d], o16[d]);
    }
  }

  // residual add + write f32 output in [B][C][H][W]
  const size_t pbase = ((size_t)b * 256 + c) * 4096 + (size_t)(ti * 4) * 64 + tj * 4;
#pragma unroll
  for (int r = 0; r < 4; ++r) {
    f32x4 bl = *(const f32x4*)(blue + pbase + r * 64);
    f32x4 ov;
#pragma unroll
    for (int j2 = 0; j2 < 4; ++j2) ov[j2] = bl[j2] + o16[r * 4 + j2] * inv;
    *(f32x4*)(out + pbase + r * 64) = ov;
  }
}

// ---------------- launcher ----------------
extern "C" void kernel_launch(void* const* d_in, const int* in_sizes, int n_in,
                              void* d_out, int out_size, void* d_ws, size_t ws_size,
                              hipStream_t stream) {
  const float* blue  = (const float*)d_in[0];
  const float* white = (const float*)d_in[1];
  const float* Wq = (const float*)d_in[2];
  const float* bq = (const float*)d_in[3];
  const float* Wk = (const float*)d_in[4];
  const float* bk = (const float*)d_in[5];
  const float* Wv = (const float*)d_in[6];
  const float* bv = (const float*)d_in[7];
  float* out = (float*)d_out;

  // workspace: Qt,Kt,Vt each [8][256 tokens][256 ch][16] bf16 = 16 MiB -> 48 MiB total
  const size_t tsz = (size_t)8 * 256 * 256 * 16;
  __bf16* Qt = (__bf16*)d_ws;
  __bf16* Kt = Qt + tsz;
  __bf16* Vt = Kt + tsz;

  proj_gemm_kernel<<<1536, 256, 0, stream>>>(blue, white, Wq, bq, Wk, bk, Wv, bv, Qt, Kt, Vt);
  attn_kernel<<<2048, 256, 0, stream>>>(Qt, Kt, Vt, blue, out);
}

// Round 2
// 89.786 us; speedup vs baseline: 1.8855x; 1.8855x over previous
//
#include <hip/hip_runtime.h>
#include <hip/hip_bf16.h>
#include <stdint.h>

typedef float  f32x4  __attribute__((ext_vector_type(4)));
typedef __bf16 bf16x8 __attribute__((ext_vector_type(8)));

// ---------------- projection GEMM ----------------
// D[o][n] = sum_c W[o][c] * X[b][c][hw(n)],  n = token-major pixel index.
// Tile: BM=128 (out-ch) x BN=128 (pixels = 8 tokens) x BK=32, 4 waves (2x2).
// Output bf16 layout: [b][ti][c][tj][16]  (tj-minor for the attention kernel).

#define BM 128
#define BN 128
#define BK 32
#define LROW 40   // bf16 elems per LDS row (32 data + 8 pad) => 80B stride, breaks bank conflicts

__global__ __launch_bounds__(256) void proj_gemm_kernel(
    const float* __restrict__ blue, const float* __restrict__ white,
    const float* __restrict__ Wq, const float* __restrict__ bq,
    const float* __restrict__ Wk, const float* __restrict__ bk,
    const float* __restrict__ Wv, const float* __restrict__ bv,
    __bf16* __restrict__ Qt, __bf16* __restrict__ Kt, __bf16* __restrict__ Vt)
{
  __shared__ __bf16 As[BM * LROW];
  __shared__ __bf16 Bs[BN * LROW];

  const int bid    = blockIdx.x;
  const int tensor = bid / 512;           // 0:Q 1:K 2:V
  const int rest   = bid - tensor * 512;
  const int ob     = rest >> 8;           // 0..1  (o-block of 128)
  const int nb     = rest & 255;          // 0..255 (n-block of 128)

  const float* X    = (tensor == 0) ? blue : white;
  const float* W    = (tensor == 0) ? Wq : (tensor == 1) ? Wk : Wv;
  const float* bias = (tensor == 0) ? bq : (tensor == 1) ? bk : bv;
  __bf16*      Out  = (tensor == 0) ? Qt : (tensor == 1) ? Kt : Vt;

  const int tid  = threadIdx.x;
  const int lane = tid & 63;
  const int wave = tid >> 6;
  const int wo   = wave >> 1;   // o half (64)
  const int wn   = wave & 1;    // n half (64)

  const int o0 = ob * BM;
  const int n0 = nb * BN;
  const int batch = n0 >> 12;         // 4096 pixels per image
  const int p0    = n0 & 4095;
  const int ti    = (p0 >> 4) >> 4;   // token row (tokens are 16-aligned in n)
  const int tj0   = (p0 >> 4) & 15;   // first token col in this tile (0 or 8)

  const float* Xb = X + (size_t)batch * (256 * 4096);

  f32x4 acc[4][4];
#pragma unroll
  for (int i = 0; i < 4; ++i)
#pragma unroll
    for (int j = 0; j < 4; ++j) acc[i][j] = (f32x4)0.0f;

  // staging roles
  const int arow  = tid >> 1;   // 0..127 weight row
  const int ahalf = tid & 1;    // 16 k's each
  const int bq5   = tid & 31;   // B: (token-local, row-in-token)
  const int btl   = bq5 >> 2;   // 0..7 token within tile
  const int brw   = bq5 & 3;    // 0..3 row within token
  const int bc8   = tid >> 5;   // 0..7 channel sub-index

  const int lrow = lane & 15;
  const int lk   = (lane >> 4) * 8;

  for (int kk = 0; kk < 8; ++kk) {
    const int k0 = kk * BK;
    // ---- stage A: W[o0..o0+127][k0..k0+31], f32 -> bf16, row-major
    {
      const float* src = W + (size_t)(o0 + arow) * 256 + k0 + ahalf * 16;
      float tmp[16] __attribute__((aligned(16)));
      *(f32x4*)(tmp + 0)  = *(const f32x4*)(src + 0);
      *(f32x4*)(tmp + 4)  = *(const f32x4*)(src + 4);
      *(f32x4*)(tmp + 8)  = *(const f32x4*)(src + 8);
      *(f32x4*)(tmp + 12) = *(const f32x4*)(src + 12);
      __bf16 cv[16] __attribute__((aligned(16)));
#pragma unroll
      for (int t = 0; t < 16; ++t) cv[t] = (__bf16)tmp[t];
      __bf16* dst = As + arow * LROW + ahalf * 16;
      *(bf16x8*)(dst + 0) = *(bf16x8*)(cv + 0);
      *(bf16x8*)(dst + 8) = *(bf16x8*)(cv + 8);
    }
    // ---- stage B: X[c][hw] -> Bs[n][c] (transpose during staging)
#pragma unroll
    for (int it = 0; it < 4; ++it) {
      const int c  = bc8 + it * 8;                       // 0..31
      const int hw = (ti * 4 + brw) * 64 + (tj0 + btl) * 4;
      const float* src = Xb + (size_t)(k0 + c) * 4096 + hw;
      f32x4 v = *(const f32x4*)src;                      // 4 pixels (d minor)
      const int nloc = btl * 16 + brw * 4;
      Bs[(nloc + 0) * LROW + c] = (__bf16)v[0];
      Bs[(nloc + 1) * LROW + c] = (__bf16)v[1];
      Bs[(nloc + 2) * LROW + c] = (__bf16)v[2];
      Bs[(nloc + 3) * LROW + c] = (__bf16)v[3];
    }
    __syncthreads();

    bf16x8 a[4], b[4];
#pragma unroll
    for (int i = 0; i < 4; ++i)
      a[i] = *(const bf16x8*)(As + (wo * 64 + i * 16 + lrow) * LROW + lk);
#pragma unroll
    for (int j = 0; j < 4; ++j)
      b[j] = *(const bf16x8*)(Bs + (wn * 64 + j * 16 + lrow) * LROW + lk);
#pragma unroll
    for (int i = 0; i < 4; ++i)
#pragma unroll
      for (int j = 0; j < 4; ++j)
        acc[i][j] = __builtin_amdgcn_mfma_f32_16x16x32_bf16(a[i], b[j], acc[i][j], 0, 0, 0);
    __syncthreads();
  }

  // ---- epilogue: bias add, write bf16 layout [b][ti][c][tj][16]
#pragma unroll
  for (int i = 0; i < 4; ++i) {
    const int obase = o0 + wo * 64 + i * 16 + (lane >> 4) * 4;
#pragma unroll
    for (int j = 0; j < 4; ++j) {
      const int n  = n0 + wn * 64 + j * 16 + (lane & 15);
      const int bb = n >> 12;
      const int p  = n & 4095;
      const int t  = p >> 4;
      const int tii = t >> 4;
      const int tjj = t & 15;
      const int d  = p & 15;
      const size_t base = ((size_t)(bb * 16 + tii) * 256) * 256 + tjj * 16 + d;
#pragma unroll
      for (int r = 0; r < 4; ++r) {
        const int o = obase + r;
        const float v = acc[i][j][r] + bias[o];
        Out[base + (size_t)o * 256] = (__bf16)v;
      }
    }
  }
}

// ---------------- fused neighborhood attention + residual ----------------
// block = (b, token-row ti, 16-channel group); thread = (c_local, tj).
// Lanes sweep tj => blue/out accesses are 256B-contiguous W rows.
// Zero-padded neighbors: OOB logit = 0 (in softmax denom), OOB V contributes 0.

__device__ __forceinline__ void unpack8(const uint4 v, float* f) {
  const uint32_t u0 = v.x, u1 = v.y, u2 = v.z, u3 = v.w;
  f[0] = __uint_as_float(u0 << 16); f[1] = __uint_as_float(u0 & 0xffff0000u);
  f[2] = __uint_as_float(u1 << 16); f[3] = __uint_as_float(u1 & 0xffff0000u);
  f[4] = __uint_as_float(u2 << 16); f[5] = __uint_as_float(u2 & 0xffff0000u);
  f[6] = __uint_as_float(u3 << 16); f[7] = __uint_as_float(u3 & 0xffff0000u);
}

__global__ __launch_bounds__(256) void attn_kernel(
    const __bf16* __restrict__ Qt, const __bf16* __restrict__ Kt,
    const __bf16* __restrict__ Vt, const float* __restrict__ blue,
    float* __restrict__ out)
{
  // XCD-chunked swizzle: 2048 blocks = 8 XCDs x 256; consecutive logical
  // blocks (same ti, different channel group) share the K/V panel in L2.
  const int j   = blockIdx.x;
  const int bid = (j & 7) * 256 + (j >> 3);
  const int cg  = bid & 15;
  const int ti  = (bid >> 4) & 15;
  const int b   = bid >> 8;

  const int tid = threadIdx.x;
  const int tj  = tid & 15;
  const int cl  = tid >> 4;
  const int c   = cg * 16 + cl;

  // index(b,yi,c,yj,d) = (((b*16+yi)*256 + c)*16 + yj)*16 + d
  float q[16];
  {
    const __bf16* p = Qt + ((((size_t)b * 16 + ti) * 256 + c) * 16 + tj) * 16;
    unpack8(*(const uint4*)p, q);
    unpack8(*(const uint4*)(p + 8), q + 8);
  }

  float s[9];
#pragma unroll
  for (int n = 0; n < 9; ++n) {
    const int yi = ti + n / 3 - 1;
    const int yj = tj + n % 3 - 1;
    float dot = 0.0f;
    if (yi >= 0 && yi < 16 && yj >= 0 && yj < 16) {
      const __bf16* p = Kt + ((((size_t)b * 16 + yi) * 256 + c) * 16 + yj) * 16;
      float kf[16];
      unpack8(*(const uint4*)p, kf);
      unpack8(*(const uint4*)(p + 8), kf + 8);
#pragma unroll
      for (int d = 0; d < 16; ++d) dot = fmaf(q[d], kf[d], dot);
    }
    s[n] = dot * 0.25f;     // scale = (ts*ts)^-0.5 ; OOB logit stays 0
  }

  float m = s[0];
#pragma unroll
  for (int n = 1; n < 9; ++n) m = fmaxf(m, s[n]);
  float w[9], denom = 0.0f;
#pragma unroll
  for (int n = 0; n < 9; ++n) { w[n] = __expf(s[n] - m); denom += w[n]; }
  const float inv = 1.0f / denom;

  float o16[16];
#pragma unroll
  for (int d = 0; d < 16; ++d) o16[d] = 0.0f;
#pragma unroll
  for (int n = 0; n < 9; ++n) {
    const int yi = ti + n / 3 - 1;
    const int yj = tj + n % 3 - 1;
    if (yi >= 0 && yi < 16 && yj >= 0 && yj < 16) {
      const __bf16* p = Vt + ((((size_t)b * 16 + yi) * 256 + c) * 16 + yj) * 16;
      float vf[16];
      unpack8(*(const uint4*)p, vf);
      unpack8(*(const uint4*)(p + 8), vf + 8);
#pragma unroll
      for (int d = 0; d < 16; ++d) o16[d] = fmaf(w[n], vf[d], o16[d]);
    }
  }

  // residual add + write f32 output in [B][C][H][W]; lanes cover a W row
  const size_t pbase = ((size_t)b * 256 + c) * 4096 + (size_t)(ti * 4) * 64 + tj * 4;
#pragma unroll
  for (int r = 0; r < 4; ++r) {
    f32x4 bl = *(const f32x4*)(blue + pbase + r * 64);
    f32x4 ov;
#pragma unroll
    for (int j2 = 0; j2 < 4; ++j2) ov[j2] = bl[j2] + o16[r * 4 + j2] * inv;
    *(f32x4*)(out + pbase + r * 64) = ov;
  }
}

// ---------------- launcher ----------------
extern "C" void kernel_launch(void* const* d_in, const int* in_sizes, int n_in,
                              void* d_out, int out_size, void* d_ws, size_t ws_size,
                              hipStream_t stream) {
  const float* blue  = (const float*)d_in[0];
  const float* white = (const float*)d_in[1];
  const float* Wq = (const float*)d_in[2];
  const float* bq = (const float*)d_in[3];
  const float* Wk = (const float*)d_in[4];
  const float* bk = (const float*)d_in[5];
  const float* Wv = (const float*)d_in[6];
  const float* bv = (const float*)d_in[7];
  float* out = (float*)d_out;

  // workspace: Qt,Kt,Vt each [8][16][256][16][16] bf16 = 16 MiB -> 48 MiB total
  const size_t tsz = (size_t)8 * 256 * 256 * 16;
  __bf16* Qt = (__bf16*)d_ws;
  __bf16* Kt = Qt + tsz;
  __bf16* Vt = Kt + tsz;

  proj_gemm_kernel<<<1536, 256, 0, stream>>>(blue, white, Wq, bq, Wk, bk, Wv, bv, Qt, Kt, Vt);
  attn_kernel<<<2048, 256, 0, stream>>>(Qt, Kt, Vt, blue, out);
}

// Round 3
// 72.701 us; speedup vs baseline: 2.3286x; 1.2350x over previous
//
#include <hip/hip_runtime.h>
#include <hip/hip_bf16.h>
#include <stdint.h>

typedef float  f32x4  __attribute__((ext_vector_type(4)));
typedef float  f32x2  __attribute__((ext_vector_type(2)));
typedef __bf16 bf16x8 __attribute__((ext_vector_type(8)));

// ---------------- projection GEMM ----------------
// D[o][n] = sum_c W[o][c] * X[b][c][hw(n)],  n = token-major pixel index.
// Tile: BM=128 (out-ch) x BN=128 (pixels) x BK=32, 4 waves (2x2).
// B staged DIRECTLY in [n][k] fragment order via k-strided global loads
// (no LDS transpose scatter -> no bank conflicts).
// Output bf16 layout: [b][ti][c][tj][16] (tj-minor for the attention kernel).

#define LROW 40   // bf16 elems per LDS row (32 data + 8 pad) => 80B stride

__global__ __launch_bounds__(256) void proj_gemm_kernel(
    const float* __restrict__ blue, const float* __restrict__ white,
    const float* __restrict__ Wq, const float* __restrict__ bq,
    const float* __restrict__ Wk, const float* __restrict__ bk,
    const float* __restrict__ Wv, const float* __restrict__ bv,
    __bf16* __restrict__ Qt, __bf16* __restrict__ Kt, __bf16* __restrict__ Vt)
{
  __shared__ __bf16 As[128 * LROW];
  __shared__ __bf16 Bs[128 * LROW];

  // XCD-chunked mapping; logical order lid = nb*6 + {K0,V0,K1,V1,Q0,Q1}
  // so K/V blocks of the same pixel tile run adjacently on one XCD
  // (second read of `white` hits that XCD's L2).
  const int bidhw = blockIdx.x;
  const int lid   = (bidhw & 7) * 192 + (bidhw >> 3);   // 1536 = 8*192
  const int nb    = lid / 6;
  const int bt    = lid % 6;
  const int tensor = (bt < 4) ? 1 + (bt & 1) : 0;   // 0:Q 1:K 2:V
  const int ob     = (bt < 4) ? (bt >> 1) : (bt & 1);

  const float* X    = (tensor == 0) ? blue : white;
  const float* W    = (tensor == 0) ? Wq : (tensor == 1) ? Wk : Wv;
  const float* bias = (tensor == 0) ? bq : (tensor == 1) ? bk : bv;
  __bf16*      Out  = (tensor == 0) ? Qt : (tensor == 1) ? Kt : Vt;

  const int tid  = threadIdx.x;
  const int lane = tid & 63;
  const int wave = tid >> 6;
  const int wo   = wave >> 1;
  const int wn   = wave & 1;

  const int o0 = ob * 128;
  const int n0 = nb * 128;
  const int batch = n0 >> 12;
  const int p0    = n0 & 4095;        // multiple of 128
  const int tk0   = p0 >> 4;          // token base (multiple of 8)
  const int trow  = tk0 >> 4;
  const int tcol0 = tk0 & 15;

  const float* Xb = X + (size_t)batch * (256 * 4096);

  f32x4 acc[4][4];
#pragma unroll
  for (int i = 0; i < 4; ++i)
#pragma unroll
    for (int j = 0; j < 4; ++j) acc[i][j] = (f32x4)0.0f;

  // ---- staging roles
  // A: thread = (row, k-half): vectorized row-major (W is k-minor already)
  const int arow  = tid >> 1;
  const int ahalf = tid & 1;
  // B: thread = (pixel-pair, k-octet): k-strided loads, fragment-order write
  const int n2   = tid & 63;         // nloc = 2*n2, 2*n2+1
  const int ko   = tid >> 6;         // 0..3
  const int nloc = 2 * n2;
  const int tl   = nloc >> 4;        // token within tile (0..7)
  const int d    = nloc & 15;        // even
  const int hw   = (trow * 4 + (d >> 2)) * 64 + (tcol0 + tl) * 4 + (d & 3);

  const int lrow = lane & 15;
  const int lk   = (lane >> 4) * 8;

  for (int kk = 0; kk < 8; ++kk) {
    const int k0 = kk * 32;
    // ---- stage A: W[o0+arow][k0 + ahalf*16 .. +15], f32 -> bf16
    {
      const float* src = W + (size_t)(o0 + arow) * 256 + k0 + ahalf * 16;
      f32x4 t0 = *(const f32x4*)(src + 0);
      f32x4 t1 = *(const f32x4*)(src + 4);
      f32x4 t2 = *(const f32x4*)(src + 8);
      f32x4 t3 = *(const f32x4*)(src + 12);
      bf16x8 c0, c1;
#pragma unroll
      for (int q = 0; q < 4; ++q) { c0[q] = (__bf16)t0[q]; c0[q + 4] = (__bf16)t1[q]; }
#pragma unroll
      for (int q = 0; q < 4; ++q) { c1[q] = (__bf16)t2[q]; c1[q + 4] = (__bf16)t3[q]; }
      __bf16* dst = As + arow * LROW + ahalf * 16;
      *(bf16x8*)(dst + 0) = c0;
      *(bf16x8*)(dst + 8) = c1;
    }
    // ---- stage B: 8 k-strided f32x2 loads -> two b128 writes in [n][k] order
    {
      const float* src = Xb + (size_t)(k0 + ko * 8) * 4096 + hw;
      f32x2 v0 = *(const f32x2*)(src + 0 * 4096);
      f32x2 v1 = *(const f32x2*)(src + 1 * 4096);
      f32x2 v2 = *(const f32x2*)(src + 2 * 4096);
      f32x2 v3 = *(const f32x2*)(src + 3 * 4096);
      f32x2 v4 = *(const f32x2*)(src + 4 * 4096);
      f32x2 v5 = *(const f32x2*)(src + 5 * 4096);
      f32x2 v6 = *(const f32x2*)(src + 6 * 4096);
      f32x2 v7 = *(const f32x2*)(src + 7 * 4096);
      bf16x8 r0, r1;
      r0[0] = (__bf16)v0[0]; r0[1] = (__bf16)v1[0]; r0[2] = (__bf16)v2[0]; r0[3] = (__bf16)v3[0];
      r0[4] = (__bf16)v4[0]; r0[5] = (__bf16)v5[0]; r0[6] = (__bf16)v6[0]; r0[7] = (__bf16)v7[0];
      r1[0] = (__bf16)v0[1]; r1[1] = (__bf16)v1[1]; r1[2] = (__bf16)v2[1]; r1[3] = (__bf16)v3[1];
      r1[4] = (__bf16)v4[1]; r1[5] = (__bf16)v5[1]; r1[6] = (__bf16)v6[1]; r1[7] = (__bf16)v7[1];
      *(bf16x8*)(Bs + (nloc + 0) * LROW + ko * 8) = r0;
      *(bf16x8*)(Bs + (nloc + 1) * LROW + ko * 8) = r1;
    }
    __syncthreads();

    bf16x8 a[4], b[4];
#pragma unroll
    for (int i = 0; i < 4; ++i)
      a[i] = *(const bf16x8*)(As + (wo * 64 + i * 16 + lrow) * LROW + lk);
#pragma unroll
    for (int j = 0; j < 4; ++j)
      b[j] = *(const bf16x8*)(Bs + (wn * 64 + j * 16 + lrow) * LROW + lk);
#pragma unroll
    for (int i = 0; i < 4; ++i)
#pragma unroll
      for (int j = 0; j < 4; ++j)
        acc[i][j] = __builtin_amdgcn_mfma_f32_16x16x32_bf16(a[i], b[j], acc[i][j], 0, 0, 0);
    __syncthreads();
  }

  // ---- epilogue: bias add, write bf16 layout [b][ti][c][tj][16]
#pragma unroll
  for (int i = 0; i < 4; ++i) {
    const int obase = o0 + wo * 64 + i * 16 + (lane >> 4) * 4;
#pragma unroll
    for (int j = 0; j < 4; ++j) {
      const int n  = n0 + wn * 64 + j * 16 + (lane & 15);
      const int bb = n >> 12;
      const int p  = n & 4095;
      const int tt = p >> 4;
      const int tii = tt >> 4;
      const int tjj = tt & 15;
      const int dd  = p & 15;
      const size_t base = ((size_t)(bb * 16 + tii) * 256) * 256 + tjj * 16 + dd;
#pragma unroll
      for (int r = 0; r < 4; ++r) {
        const int o = obase + r;
        const float v = acc[i][j][r] + bias[o];
        Out[base + (size_t)o * 256] = (__bf16)v;
      }
    }
  }
}

// ---------------- fused neighborhood attention + residual ----------------
__device__ __forceinline__ void unpack8(const uint4 v, float* f) {
  const uint32_t u0 = v.x, u1 = v.y, u2 = v.z, u3 = v.w;
  f[0] = __uint_as_float(u0 << 16); f[1] = __uint_as_float(u0 & 0xffff0000u);
  f[2] = __uint_as_float(u1 << 16); f[3] = __uint_as_float(u1 & 0xffff0000u);
  f[4] = __uint_as_float(u2 << 16); f[5] = __uint_as_float(u2 & 0xffff0000u);
  f[6] = __uint_as_float(u3 << 16); f[7] = __uint_as_float(u3 & 0xffff0000u);
}

__global__ __launch_bounds__(256) void attn_kernel(
    const __bf16* __restrict__ Qt, const __bf16* __restrict__ Kt,
    const __bf16* __restrict__ Vt, const float* __restrict__ blue,
    float* __restrict__ out)
{
  const int j   = blockIdx.x;
  const int bid = (j & 7) * 256 + (j >> 3);
  const int cg  = bid & 15;
  const int ti  = (bid >> 4) & 15;
  const int b   = bid >> 8;

  const int tid = threadIdx.x;
  const int tj  = tid & 15;
  const int cl  = tid >> 4;
  const int c   = cg * 16 + cl;

  float q[16];
  {
    const __bf16* p = Qt + ((((size_t)b * 16 + ti) * 256 + c) * 16 + tj) * 16;
    unpack8(*(const uint4*)p, q);
    unpack8(*(const uint4*)(p + 8), q + 8);
  }

  float s[9];
#pragma unroll
  for (int n = 0; n < 9; ++n) {
    const int yi = ti + n / 3 - 1;
    const int yj = tj + n % 3 - 1;
    float dot = 0.0f;
    if (yi >= 0 && yi < 16 && yj >= 0 && yj < 16) {
      const __bf16* p = Kt + ((((size_t)b * 16 + yi) * 256 + c) * 16 + yj) * 16;
      float kf[16];
      unpack8(*(const uint4*)p, kf);
      unpack8(*(const uint4*)(p + 8), kf + 8);
#pragma unroll
      for (int d = 0; d < 16; ++d) dot = fmaf(q[d], kf[d], dot);
    }
    s[n] = dot * 0.25f;
  }

  float m = s[0];
#pragma unroll
  for (int n = 1; n < 9; ++n) m = fmaxf(m, s[n]);
  float w[9], denom = 0.0f;
#pragma unroll
  for (int n = 0; n < 9; ++n) { w[n] = __expf(s[n] - m); denom += w[n]; }
  const float inv = 1.0f / denom;

  float o16[16];
#pragma unroll
  for (int d = 0; d < 16; ++d) o16[d] = 0.0f;
#pragma unroll
  for (int n = 0; n < 9; ++n) {
    const int yi = ti + n / 3 - 1;
    const int yj = tj + n % 3 - 1;
    if (yi >= 0 && yi < 16 && yj >= 0 && yj < 16) {
      const __bf16* p = Vt + ((((size_t)b * 16 + yi) * 256 + c) * 16 + yj) * 16;
      float vf[16];
      unpack8(*(const uint4*)p, vf);
      unpack8(*(const uint4*)(p + 8), vf + 8);
#pragma unroll
      for (int d = 0; d < 16; ++d) o16[d] = fmaf(w[n], vf[d], o16[d]);
    }
  }

  const size_t pbase = ((size_t)b * 256 + c) * 4096 + (size_t)(ti * 4) * 64 + tj * 4;
#pragma unroll
  for (int r = 0; r < 4; ++r) {
    f32x4 bl = *(const f32x4*)(blue + pbase + r * 64);
    f32x4 ov;
#pragma unroll
    for (int j2 = 0; j2 < 4; ++j2) ov[j2] = bl[j2] + o16[r * 4 + j2] * inv;
    *(f32x4*)(out + pbase + r * 64) = ov;
  }
}

// ---------------- launcher ----------------
extern "C" void kernel_launch(void* const* d_in, const int* in_sizes, int n_in,
                              void* d_out, int out_size, void* d_ws, size_t ws_size,
                              hipStream_t stream) {
  const float* blue  = (const float*)d_in[0];
  const float* white = (const float*)d_in[1];
  const float* Wq = (const float*)d_in[2];
  const float* bq = (const float*)d_in[3];
  const float* Wk = (const float*)d_in[4];
  const float* bk = (const float*)d_in[5];
  const float* Wv = (const float*)d_in[6];
  const float* bv = (const float*)d_in[7];
  float* out = (float*)d_out;

  const size_t tsz = (size_t)8 * 256 * 256 * 16;
  __bf16* Qt = (__bf16*)d_ws;
  __bf16* Kt = Qt + tsz;
  __bf16* Vt = Kt + tsz;

  proj_gemm_kernel<<<1536, 256, 0, stream>>>(blue, white, Wq, bq, Wk, bk, Wv, bv, Qt, Kt, Vt);
  attn_kernel<<<2048, 256, 0, stream>>>(Qt, Kt, Vt, blue, out);
}